// Round 3
// baseline (524.847 us; speedup 1.0000x reference)
//
#include <hip/hip_runtime.h>
#include <hip/hip_bf16.h>

#define BATCH 32
#define CDIM  256
#define TDIM  4096
#define SPLIT 8            // K-split chunks for gram
#define KCH   (TDIM / SPLIT)   // 512
#define BK    32
#define NIT   (KCH / BK)       // 16

using short8  = __attribute__((ext_vector_type(8))) short;
using floatx4 = __attribute__((ext_vector_type(4))) float;

// RNE float -> bf16 (finite inputs)
__device__ __forceinline__ unsigned f2bf(float f) {
  unsigned u = __float_as_uint(f);
  return (u + 0x7fffu + ((u >> 16) & 1u)) >> 16;
}
__device__ __forceinline__ unsigned cvt_pk_bf16(float a, float b) {
  return f2bf(a) | (f2bf(b) << 16);
}
__device__ __forceinline__ float bf_lo(unsigned u) { return __uint_as_float(u << 16); }
__device__ __forceinline__ float bf_hi(unsigned u) { return __uint_as_float(u & 0xffff0000u); }

// 4 floats -> 2 packed h words + 2 packed l words (h = bf16 RNE, l = bf16(x-h))
__device__ __forceinline__ void cvt4(const float4 v, unsigned& h0, unsigned& h1,
                                     unsigned& l0, unsigned& l1) {
  h0 = cvt_pk_bf16(v.x, v.y);
  h1 = cvt_pk_bf16(v.z, v.w);
  l0 = cvt_pk_bf16(v.x - bf_lo(h0), v.y - bf_hi(h0));
  l1 = cvt_pk_bf16(v.z - bf_lo(h1), v.w - bf_hi(h1));
}

// ---------------------------------------------------------------------------
// Gram (symmetric): energy = h h^T + l h^T + h l^T, accumulated in ONE acc.
// Per batch: tiles (0,0),(1,1) diag + (0,1) upper. Off-diag writes [I,J] and
// (via LDS transpose bounce) [J,I]. K-split SPLIT chunks -> atomicAdd into
// zeroed energy. Grid = 32 * 3 * SPLIT = 768 blocks, 256 thr (4 waves, 2x2,
// wave tile 64x64 = 4x4 frags of 16x16x32). 48 MFMA per barrier pair.
// ---------------------------------------------------------------------------
__global__ __launch_bounds__(256, 2)
void gram_sym(const float* __restrict__ x, float* __restrict__ energy) {
  // staging: 4 x (128 rows x 40 shorts) = 40960 B; epilogue tbuf 64x129 fp32
  // = 33024 B aliased on top (guarded by __syncthreads).
  __shared__ __align__(16) char smem[4 * 128 * 40 * 2];
  short* hIs = (short*)smem;
  short* lIs = hIs + 128 * 40;
  short* hJs = lIs + 128 * 40;
  short* lJs = hJs + 128 * 40;
  float* tbuf = (float*)smem;

  const int tid  = threadIdx.x;
  const int bx   = blockIdx.x;
  const int b    = bx / (3 * SPLIT);
  const int rem  = bx % (3 * SPLIT);
  const int tile = rem / SPLIT;       // 0:(0,0) 1:(128,128) 2:(0,128)
  const int kc   = rem % SPLIT;
  const bool diag = (tile < 2);
  const int I0 = (tile == 1) ? 128 : 0;
  const int J0 = (tile == 0) ? 0 : 128;

  const float* xb = x + ((size_t)b << 20);
  float* eb = energy + ((size_t)b << 16);

  // staging map: 2 threads per row, 16 floats each
  const int srow = tid >> 1;
  const int scol = (tid & 1) << 4;
  const float* pI = xb + (size_t)(I0 + srow) * TDIM + kc * KCH + scol;
  const float* pJ = xb + (size_t)(J0 + srow) * TDIM + kc * KCH + scol;

  floatx4 acc[4][4];
#pragma unroll
  for (int m = 0; m < 4; ++m)
#pragma unroll
    for (int n = 0; n < 4; ++n) acc[m][n] = {0.f, 0.f, 0.f, 0.f};

  const int lane = tid & 63;
  const int w    = tid >> 6;
  const int wm   = (w >> 1) << 6;   // 0 / 64
  const int wn   = (w & 1) << 6;    // 0 / 64
  const int fr   = lane & 15;
  const int q    = lane >> 4;

  // prefetch first K-step
  float4 rI[4], rJ[4];
#pragma unroll
  for (int u = 0; u < 4; ++u) rI[u] = *(const float4*)(pI + 4 * u);
  if (!diag) {
#pragma unroll
    for (int u = 0; u < 4; ++u) rJ[u] = *(const float4*)(pJ + 4 * u);
  }

  for (int ks = 0; ks < NIT; ++ks) {
    unsigned hw[8], lw[8], hwj[8], lwj[8];
#pragma unroll
    for (int u = 0; u < 4; ++u)
      cvt4(rI[u], hw[2 * u], hw[2 * u + 1], lw[2 * u], lw[2 * u + 1]);
    if (!diag) {
#pragma unroll
      for (int u = 0; u < 4; ++u)
        cvt4(rJ[u], hwj[2 * u], hwj[2 * u + 1], lwj[2 * u], lwj[2 * u + 1]);
    }

    __syncthreads();
    *(uint4*)&hIs[srow * 40 + scol]     = make_uint4(hw[0], hw[1], hw[2], hw[3]);
    *(uint4*)&hIs[srow * 40 + scol + 8] = make_uint4(hw[4], hw[5], hw[6], hw[7]);
    *(uint4*)&lIs[srow * 40 + scol]     = make_uint4(lw[0], lw[1], lw[2], lw[3]);
    *(uint4*)&lIs[srow * 40 + scol + 8] = make_uint4(lw[4], lw[5], lw[6], lw[7]);
    if (!diag) {
      *(uint4*)&hJs[srow * 40 + scol]     = make_uint4(hwj[0], hwj[1], hwj[2], hwj[3]);
      *(uint4*)&hJs[srow * 40 + scol + 8] = make_uint4(hwj[4], hwj[5], hwj[6], hwj[7]);
      *(uint4*)&lJs[srow * 40 + scol]     = make_uint4(lwj[0], lwj[1], lwj[2], lwj[3]);
      *(uint4*)&lJs[srow * 40 + scol + 8] = make_uint4(lwj[4], lwj[5], lwj[6], lwj[7]);
    }
    __syncthreads();

    if (ks < NIT - 1) {
      pI += BK;
#pragma unroll
      for (int u = 0; u < 4; ++u) rI[u] = *(const float4*)(pI + 4 * u);
      if (!diag) {
        pJ += BK;
#pragma unroll
        for (int u = 0; u < 4; ++u) rJ[u] = *(const float4*)(pJ + 4 * u);
      }
    }

    const short* hB = diag ? hIs : hJs;
    const short* lB = diag ? lIs : lJs;

    short8 Ah[4], Al[4], Bh[4], Bl[4];
#pragma unroll
    for (int m = 0; m < 4; ++m) {
      Ah[m] = *(const short8*)&hIs[(wm + 16 * m + fr) * 40 + q * 8];
      Al[m] = *(const short8*)&lIs[(wm + 16 * m + fr) * 40 + q * 8];
    }
#pragma unroll
    for (int n = 0; n < 4; ++n) {
      Bh[n] = *(const short8*)&hB[(wn + 16 * n + fr) * 40 + q * 8];
      Bl[n] = *(const short8*)&lB[(wn + 16 * n + fr) * 40 + q * 8];
    }
#pragma unroll
    for (int m = 0; m < 4; ++m)
#pragma unroll
      for (int n = 0; n < 4; ++n) {
        acc[m][n] = __builtin_amdgcn_mfma_f32_16x16x32_bf16(Ah[m], Bh[n], acc[m][n], 0, 0, 0);
        acc[m][n] = __builtin_amdgcn_mfma_f32_16x16x32_bf16(Al[m], Bh[n], acc[m][n], 0, 0, 0);
        acc[m][n] = __builtin_amdgcn_mfma_f32_16x16x32_bf16(Ah[m], Bl[n], acc[m][n], 0, 0, 0);
      }
  }

  // direct write [I,J] (C/D layout: col = lane&15, row = (lane>>4)*4 + reg)
#pragma unroll
  for (int m = 0; m < 4; ++m)
#pragma unroll
    for (int n = 0; n < 4; ++n) {
      const int gr = I0 + wm + 16 * m + 4 * q;
      const int gc = J0 + wn + 16 * n + fr;
#pragma unroll
      for (int r = 0; r < 4; ++r)
        atomicAdd(&eb[((gr + r) << 8) + gc], acc[m][n][r]);
    }

  // transposed write [J,I] via LDS bounce, 64-row halves
  if (!diag) {
#pragma unroll
    for (int h = 0; h < 2; ++h) {
      __syncthreads();
      if (wm == (h << 6)) {
#pragma unroll
        for (int m = 0; m < 4; ++m)
#pragma unroll
          for (int n = 0; n < 4; ++n)
#pragma unroll
            for (int r = 0; r < 4; ++r)
              tbuf[(16 * m + 4 * q + r) * 129 + wn + 16 * n + fr] = acc[m][n][r];
      }
      __syncthreads();
      const int jr = tid >> 1;
      const int cb = (tid & 1) << 5;
#pragma unroll
      for (int k2 = 0; k2 < 32; ++k2) {
        float v = tbuf[(cb + k2) * 129 + jr];
        atomicAdd(&eb[((J0 + jr) << 8) + I0 + (h << 6) + cb + k2], v);
      }
    }
  }
}

// ---------------------------------------------------------------------------
// Softmax: att = softmax(-energy) per row; one block (256 thr) per (b, i)
// ---------------------------------------------------------------------------
__global__ __launch_bounds__(256)
void softmax_kernel(const float* __restrict__ energy, __hip_bfloat16* __restrict__ att) {
  const int b = blockIdx.x >> 8;
  const int i = blockIdx.x & 255;
  const int j = threadIdx.x;
  const size_t base = (size_t)b << 16;

  float z = -energy[base + (i << 8) + j];

  float m = z;
#pragma unroll
  for (int off = 32; off > 0; off >>= 1) m = fmaxf(m, __shfl_xor(m, off, 64));

  __shared__ float red[8];
  const int wv = j >> 6, ln = j & 63;
  if (ln == 0) red[wv] = m;
  __syncthreads();
  m = fmaxf(fmaxf(red[0], red[1]), fmaxf(red[2], red[3]));

  float p = expf(z - m);
  float s = p;
#pragma unroll
  for (int off = 32; off > 0; off >>= 1) s += __shfl_xor(s, off, 64);
  if (ln == 0) red[4 + wv] = s;
  __syncthreads();
  s = (red[4] + red[5]) + (red[6] + red[7]);

  att[base + (i << 8) + j] = __float2bfloat16(p / s);
}

// ---------------------------------------------------------------------------
// PV: out = gamma * (att @ x) + x   (unchanged from round 2)
// ---------------------------------------------------------------------------
__global__ __launch_bounds__(256, 2)
void pv_kernel(const float* __restrict__ x, const __hip_bfloat16* __restrict__ att,
               const float* __restrict__ gamma, float* __restrict__ out) {
  __shared__ __align__(16) short As[128 * 40];
  __shared__ __align__(16) short Bt[128 * 40];

  const int tid = threadIdx.x;
  const int bx  = blockIdx.x;
  const int b   = bx >> 6;
  const int i0  = ((bx >> 5) & 1) << 7;
  const int t0  = (bx & 31) << 7;

  const float* xb = x + ((size_t)b << 20);
  const unsigned short* attb = (const unsigned short*)att + ((size_t)b << 16);

  const int arow = tid >> 1;
  const int aoff = (tid & 1) << 4;
  const int kg = tid >> 5;
  const int tg = tid & 31;

  floatx4 acc[4][4];
#pragma unroll
  for (int m = 0; m < 4; ++m)
#pragma unroll
    for (int n = 0; n < 4; ++n) acc[m][n] = {0.f, 0.f, 0.f, 0.f};

  const int lane = tid & 63;
  const int w    = tid >> 6;
  const int wm   = (w >> 1) << 6;
  const int wn   = (w & 1) << 6;
  const int fr   = lane & 15;
  const int q    = lane >> 4;

  const unsigned short* pA = attb + (size_t)(i0 + arow) * CDIM + aoff;
  const float* pB = xb + (size_t)(kg * 4) * TDIM + t0 + tg;

  uint4 ra0 = *(const uint4*)pA;
  uint4 ra1 = *(const uint4*)(pA + 8);
  float xv[4][4];
#pragma unroll
  for (int kk = 0; kk < 4; ++kk)
#pragma unroll
    for (int tt = 0; tt < 4; ++tt) xv[kk][tt] = pB[kk * TDIM + tt * 32];

  for (int ks = 0; ks < CDIM / 32; ++ks) {
    unsigned bu[4][2];
#pragma unroll
    for (int tt = 0; tt < 4; ++tt) {
      bu[tt][0] = cvt_pk_bf16(xv[0][tt], xv[1][tt]);
      bu[tt][1] = cvt_pk_bf16(xv[2][tt], xv[3][tt]);
    }

    __syncthreads();
    *(uint4*)(&As[arow * 40 + aoff])     = ra0;
    *(uint4*)(&As[arow * 40 + aoff + 8]) = ra1;
#pragma unroll
    for (int tt = 0; tt < 4; ++tt)
      *(uint2*)(&Bt[(tg + tt * 32) * 40 + kg * 4]) = make_uint2(bu[tt][0], bu[tt][1]);
    __syncthreads();

    if (ks < CDIM / 32 - 1) {
      pA += 32; pB += (size_t)32 * TDIM;
      ra0 = *(const uint4*)pA;
      ra1 = *(const uint4*)(pA + 8);
#pragma unroll
      for (int kk = 0; kk < 4; ++kk)
#pragma unroll
        for (int tt = 0; tt < 4; ++tt) xv[kk][tt] = pB[kk * TDIM + tt * 32];
    }

    short8 Af[4], Bf[4];
#pragma unroll
    for (int m = 0; m < 4; ++m) Af[m] = *(const short8*)(&As[(wm + 16 * m + fr) * 40 + q * 8]);
#pragma unroll
    for (int n = 0; n < 4; ++n) Bf[n] = *(const short8*)(&Bt[(wn + 16 * n + fr) * 40 + q * 8]);
#pragma unroll
    for (int m = 0; m < 4; ++m)
#pragma unroll
      for (int n = 0; n < 4; ++n)
        acc[m][n] = __builtin_amdgcn_mfma_f32_16x16x32_bf16(Af[m], Bf[n], acc[m][n], 0, 0, 0);
  }

  const float g = gamma[0];
#pragma unroll
  for (int m = 0; m < 4; ++m)
#pragma unroll
    for (int n = 0; n < 4; ++n) {
      const int gr = i0 + wm + 16 * m + 4 * q;
      const int gc = t0 + wn + 16 * n + fr;
      size_t base = ((size_t)b << 20) + (size_t)gr * TDIM + gc;
#pragma unroll
      for (int r = 0; r < 4; ++r) {
        size_t idx = base + (size_t)r * TDIM;
        out[idx] = g * acc[m][n][r] + x[idx];
      }
    }
}

// ---------------------------------------------------------------------------
extern "C" void kernel_launch(void* const* d_in, const int* in_sizes, int n_in,
                              void* d_out, int out_size, void* d_ws, size_t ws_size,
                              hipStream_t stream) {
  (void)in_sizes; (void)n_in; (void)out_size; (void)ws_size;
  const float* x     = (const float*)d_in[0];
  const float* gamma = (const float*)d_in[1];
  float* out = (float*)d_out;

  const size_t EN = (size_t)BATCH * CDIM * CDIM;  // 2,097,152
  float* energy = (float*)d_ws;                   // 8 MiB
  __hip_bfloat16* att = (__hip_bfloat16*)(energy + EN);  // 4 MiB  (ws total 12 MiB)

  hipMemsetAsync(energy, 0, EN * sizeof(float), stream);
  gram_sym<<<dim3(BATCH * 3 * SPLIT), dim3(256), 0, stream>>>(x, energy);
  softmax_kernel<<<dim3(BATCH * CDIM), dim3(256), 0, stream>>>(energy, att);
  pv_kernel<<<dim3(2048), dim3(256), 0, stream>>>(x, att, gamma, out);
}